// Round 6
// baseline (571.577 us; speedup 1.0000x reference)
//
#include <hip/hip_runtime.h>
#include <math.h>

#define T_SEQ 2048
#define C_DIM 1024
#define NHEAD 16
#define HDIM 64
#define M_ROWS 4096   // B*T
#define N_QKV 3072    // 3*C

typedef __attribute__((ext_vector_type(8))) short short8;   // 8 bf16 (4 VGPR)
typedef __attribute__((ext_vector_type(4))) float f32x4;    // MFMA C/D
typedef unsigned short ushort_t;

__device__ inline unsigned short f2bf(float x) {            // RNE f32->bf16
  union { float f; unsigned u; } v; v.f = x;
  unsigned r = v.u + 0x7FFF + ((v.u >> 16) & 1);
  return (unsigned short)(r >> 16);
}
__device__ inline float bf2f(unsigned short h) {
  union { unsigned u; float f; } v; v.u = ((unsigned)h) << 16; return v.f;
}

// async global->LDS, 16B per lane; LDS dest = wave-uniform base + lane*16
__device__ __forceinline__ void gll16(const char* g, char* l) {
  __builtin_amdgcn_global_load_lds(
      (const __attribute__((address_space(1))) unsigned*)g,
      (__attribute__((address_space(3))) unsigned*)l, 16, 0, 0);
}

// ---------------- abs-mean scale (deterministic 2-stage reduction) ----------
__global__ __launch_bounds__(256) void abs_partial_k(const float* __restrict__ w,
                                                     int n, float* __restrict__ part) {
  __shared__ float red[256];
  float s = 0.f;
  for (int i = blockIdx.x * 256 + threadIdx.x; i < n; i += 256 * 256)
    s += fabsf(w[i]);
  red[threadIdx.x] = s;
  __syncthreads();
  for (int st = 128; st > 0; st >>= 1) {
    if ((int)threadIdx.x < st) red[threadIdx.x] += red[threadIdx.x + st];
    __syncthreads();
  }
  if (threadIdx.x == 0) part[blockIdx.x] = red[0];
}

__global__ __launch_bounds__(256) void finalize_scales_k(const float* __restrict__ part,
                                                         float* __restrict__ scales) {
  __shared__ float red[256];
  red[threadIdx.x] = part[blockIdx.x * 256 + threadIdx.x];
  __syncthreads();
  for (int st = 128; st > 0; st >>= 1) {
    if ((int)threadIdx.x < st) red[threadIdx.x] += red[threadIdx.x + st];
    __syncthreads();
  }
  if (threadIdx.x == 0) {
    float n = (blockIdx.x == 0) ? (float)(N_QKV * C_DIM) : (float)(C_DIM * C_DIM);
    scales[blockIdx.x] = fmaxf(red[0] / n, 1e-8f);
  }
}

// ---------------- ternarize -> bf16 (exact: {-1,0,1}) -----------------------
__global__ __launch_bounds__(256) void ternarize_k(const float* __restrict__ w,
                                                   ushort_t* __restrict__ wt, int n,
                                                   const float* __restrict__ scales,
                                                   int which) {
  int i = blockIdx.x * 256 + threadIdx.x;
  if (i < n) {
    float s = scales[which];
    float t = rintf(w[i] / s);           // round-half-even matches jnp.round
    wt[i] = f2bf(fminf(1.f, fmaxf(-1.f, t)));
  }
}

// ---------------- fp32 -> bf16 hi/lo split ----------------------------------
__global__ __launch_bounds__(256) void split_hl_k(const float* __restrict__ in,
                                                  ushort_t* __restrict__ hi,
                                                  ushort_t* __restrict__ lo, int n4) {
  int i = blockIdx.x * 256 + threadIdx.x;
  if (i < n4) {
    const float4 v = ((const float4*)in)[i];
    const float vv[4] = {v.x, v.y, v.z, v.w};
    ushort_t hh[4], ll[4];
#pragma unroll
    for (int j = 0; j < 4; ++j) {
      hh[j] = f2bf(vv[j]);
      ll[j] = f2bf(vv[j] - bf2f(hh[j]));
    }
    ((ushort4*)hi)[i] = make_ushort4(hh[0], hh[1], hh[2], hh[3]);
    ((ushort4*)lo)[i] = make_ushort4(ll[0], ll[1], ll[2], ll[3]);
  }
}

// ---------------- bf16 MFMA GEMM, A split hi/lo (qkv projection) ------------
// C[m][n] = sum_k (Ah+Al)[m][k] * Bw[n][k]; tile 128x128, BK=64, 4 waves 2x2.
// LDS rows 128B, XOR-swizzled (T2) -> conflict-free ds_read_b128.
__global__ __launch_bounds__(256) void gemm_bf16_hl(const ushort_t* __restrict__ Ah,
                                                    const ushort_t* __restrict__ Al,
                                                    const ushort_t* __restrict__ Bw,
                                                    float* __restrict__ C,
                                                    int Nd, int Kd) {
  __shared__ __align__(16) ushort_t Ash[128 * 64];
  __shared__ __align__(16) ushort_t Asl[128 * 64];
  __shared__ __align__(16) ushort_t Bs[128 * 64];
  const int tid = threadIdx.x;
  const int bm = blockIdx.y << 7, bn = blockIdx.x << 7;
  const int w = tid >> 6, lane = tid & 63;
  const int wm = (w >> 1) << 6, wn = (w & 1) << 6;
  const int fr = lane & 15, fc = lane >> 4;
  const int srow = tid >> 1;                 // staging row 0..127
  const int sv0 = (tid & 1) << 2;            // 16B-slot base: 0 or 4
  const int swz = (srow & 7) << 4;
  const size_t arow = (size_t)(bm + srow) * Kd;
  const size_t brow = (size_t)(bn + srow) * Kd;
  int wb[4];
#pragma unroll
  for (int j = 0; j < 4; ++j) wb[j] = srow * 128 + (((sv0 + j) << 4) ^ swz);

  f32x4 acc[4][4];
  const f32x4 z = {0.f, 0.f, 0.f, 0.f};
#pragma unroll
  for (int i = 0; i < 4; ++i)
#pragma unroll
    for (int j = 0; j < 4; ++j) acc[i][j] = z;

  for (int k0 = 0; k0 < Kd; k0 += 64) {
    const int gcol = k0 + (sv0 << 3);        // elem col: k0 + (tid&1)*32
    short8 sa[4], sl[4], sb[4];
#pragma unroll
    for (int j = 0; j < 4; ++j) {
      sa[j] = *(const short8*)(Ah + arow + gcol + j * 8);
      sl[j] = *(const short8*)(Al + arow + gcol + j * 8);
      sb[j] = *(const short8*)(Bw + brow + gcol + j * 8);
    }
    __syncthreads();
#pragma unroll
    for (int j = 0; j < 4; ++j) {
      *(short8*)((char*)Ash + wb[j]) = sa[j];
      *(short8*)((char*)Asl + wb[j]) = sl[j];
      *(short8*)((char*)Bs  + wb[j]) = sb[j];
    }
    __syncthreads();
#pragma unroll
    for (int ks = 0; ks < 2; ++ks) {
      short8 af[4], lf[4], bf[4];
#pragma unroll
      for (int i = 0; i < 4; ++i) {
        const int ra = wm + i * 16 + fr;
        af[i] = *(const short8*)((const char*)Ash + ra * 128 + ((ks * 64 + fc * 16) ^ ((ra & 7) << 4)));
        lf[i] = *(const short8*)((const char*)Asl + ra * 128 + ((ks * 64 + fc * 16) ^ ((ra & 7) << 4)));
        const int rb = wn + i * 16 + fr;
        bf[i] = *(const short8*)((const char*)Bs + rb * 128 + ((ks * 64 + fc * 16) ^ ((rb & 7) << 4)));
      }
#pragma unroll
      for (int i = 0; i < 4; ++i)
#pragma unroll
        for (int j = 0; j < 4; ++j) {
          acc[i][j] = __builtin_amdgcn_mfma_f32_16x16x32_bf16(af[i], bf[j], acc[i][j], 0, 0, 0);
          acc[i][j] = __builtin_amdgcn_mfma_f32_16x16x32_bf16(lf[i], bf[j], acc[i][j], 0, 0, 0);
        }
    }
  }
#pragma unroll
  for (int i = 0; i < 4; ++i)
#pragma unroll
    for (int j = 0; j < 4; ++j) {
      float* cp = C + (size_t)(bm + wm + i * 16 + fc * 4) * Nd + bn + wn + j * 16 + fr;
#pragma unroll
      for (int r = 0; r < 4; ++r) cp[(size_t)r * Nd] = acc[i][j][r];
    }
}

// ---------------- bf16 MFMA GEMM, single-pass A (out projection) ------------
__global__ __launch_bounds__(256) void gemm_bf16(const ushort_t* __restrict__ A,
                                                 const ushort_t* __restrict__ Bw,
                                                 float* __restrict__ C,
                                                 int Nd, int Kd) {
  __shared__ __align__(16) ushort_t Ash[128 * 64];
  __shared__ __align__(16) ushort_t Bs[128 * 64];
  const int tid = threadIdx.x;
  const int bm = blockIdx.y << 7, bn = blockIdx.x << 7;
  const int w = tid >> 6, lane = tid & 63;
  const int wm = (w >> 1) << 6, wn = (w & 1) << 6;
  const int fr = lane & 15, fc = lane >> 4;
  const int srow = tid >> 1;
  const int sv0 = (tid & 1) << 2;
  const int swz = (srow & 7) << 4;
  const size_t arow = (size_t)(bm + srow) * Kd;
  const size_t brow = (size_t)(bn + srow) * Kd;
  int wb[4];
#pragma unroll
  for (int j = 0; j < 4; ++j) wb[j] = srow * 128 + (((sv0 + j) << 4) ^ swz);

  f32x4 acc[4][4];
  const f32x4 z = {0.f, 0.f, 0.f, 0.f};
#pragma unroll
  for (int i = 0; i < 4; ++i)
#pragma unroll
    for (int j = 0; j < 4; ++j) acc[i][j] = z;

  for (int k0 = 0; k0 < Kd; k0 += 64) {
    const int gcol = k0 + (sv0 << 3);
    short8 sa[4], sb[4];
#pragma unroll
    for (int j = 0; j < 4; ++j) {
      sa[j] = *(const short8*)(A + arow + gcol + j * 8);
      sb[j] = *(const short8*)(Bw + brow + gcol + j * 8);
    }
    __syncthreads();
#pragma unroll
    for (int j = 0; j < 4; ++j) {
      *(short8*)((char*)Ash + wb[j]) = sa[j];
      *(short8*)((char*)Bs  + wb[j]) = sb[j];
    }
    __syncthreads();
#pragma unroll
    for (int ks = 0; ks < 2; ++ks) {
      short8 af[4], bf[4];
#pragma unroll
      for (int i = 0; i < 4; ++i) {
        const int ra = wm + i * 16 + fr;
        af[i] = *(const short8*)((const char*)Ash + ra * 128 + ((ks * 64 + fc * 16) ^ ((ra & 7) << 4)));
        const int rb = wn + i * 16 + fr;
        bf[i] = *(const short8*)((const char*)Bs + rb * 128 + ((ks * 64 + fc * 16) ^ ((rb & 7) << 4)));
      }
#pragma unroll
      for (int i = 0; i < 4; ++i)
#pragma unroll
        for (int j = 0; j < 4; ++j)
          acc[i][j] = __builtin_amdgcn_mfma_f32_16x16x32_bf16(af[i], bf[j], acc[i][j], 0, 0, 0);
    }
  }
#pragma unroll
  for (int i = 0; i < 4; ++i)
#pragma unroll
    for (int j = 0; j < 4; ++j) {
      float* cp = C + (size_t)(bm + wm + i * 16 + fc * 4) * Nd + bn + wn + j * 16 + fr;
#pragma unroll
      for (int r = 0; r < 4; ++r) cp[(size_t)r * Nd] = acc[i][j][r];
    }
}

// ---------------- prep_kv: per-(b,h,chunk) swizzled LDS images --------------
__global__ __launch_bounds__(256) void prep_kv_k(const float* __restrict__ qkv,
                                                 char* __restrict__ img) {
  __shared__ __align__(16) char sm[24576];
  const int tid = threadIdx.x;
  const int c = blockIdx.x & 31, gg = blockIdx.x >> 5;
  const int h = gg & 15, b = gg >> 4;
  const int key = tid >> 2, dg = tid & 3;
  const float* kp = qkv + (size_t)b * T_SEQ * N_QKV +
                    (size_t)(c * 64 + key) * N_QKV + C_DIM + (h << 6) + dg * 16;
  const float4 k0 = *(const float4*)(kp + 0);
  const float4 k1 = *(const float4*)(kp + 4);
  const float4 k2 = *(const float4*)(kp + 8);
  const float4 k3 = *(const float4*)(kp + 12);
  const float4 v0 = *(const float4*)(kp + C_DIM + 0);
  const float4 v1 = *(const float4*)(kp + C_DIM + 4);
  const float4 v2 = *(const float4*)(kp + C_DIM + 8);
  const float4 v3 = *(const float4*)(kp + C_DIM + 12);
  const float kv[16] = {k0.x,k0.y,k0.z,k0.w, k1.x,k1.y,k1.z,k1.w,
                        k2.x,k2.y,k2.z,k2.w, k3.x,k3.y,k3.z,k3.w};
  const float vv[16] = {v0.x,v0.y,v0.z,v0.w, v1.x,v1.y,v1.z,v1.w,
                        v2.x,v2.y,v2.z,v2.w, v3.x,v3.y,v3.z,v3.w};
  short8 khi0, khi1, klo0, klo1;
#pragma unroll
  for (int j = 0; j < 8; ++j) {
    const float x0 = kv[j], x1 = kv[8 + j];
    const unsigned short h0 = f2bf(x0), h1 = f2bf(x1);
    khi0[j] = (short)h0; khi1[j] = (short)h1;
    klo0[j] = (short)f2bf(x0 - bf2f(h0));
    klo1[j] = (short)f2bf(x1 - bf2f(h1));
  }
  const int sw = (key & 7) << 4;
  const int b0 = key * 128 + ((dg * 32) ^ sw);
  const int b1 = key * 128 + ((dg * 32 + 16) ^ sw);
  *(short8*)(sm + b0) = khi0;        *(short8*)(sm + b1) = khi1;
  *(short8*)(sm + 8192 + b0) = klo0; *(short8*)(sm + 8192 + b1) = klo1;
#pragma unroll
  for (int i = 0; i < 16; ++i) {
    const int d = dg * 16 + i;
    *(short*)(sm + 16384 + d * 128 + ((key * 2) ^ ((d & 7) << 4))) = (short)f2bf(vv[i]);
  }
  __syncthreads();
  int4* dst = (int4*)(img + (size_t)blockIdx.x * 24576);
  const int4* src = (const int4*)sm;
#pragma unroll
  for (int i = 0; i < 6; ++i) dst[i * 256 + tid] = src[i * 256 + tid];
}

// ---------------- paired-tile MFMA flash attention --------------------------
// Single-buffered 24KB chunk image + 8KB P = 32KB LDS -> 5 blocks/CU (TLP
// hides the per-chunk load stall across blocks). 33 tile-computes per block.
struct TS { f32x4 O[4]; float m[4]; float l[4]; };

__device__ __forceinline__ void tile_step(const char* khp, const char* klp,
                                          const char* vTp, char* pp,
                                          const short8* qh, const short8* ql,
                                          TS& st, const bool diag,
                                          const int w, const int lg, const int lr) {
  f32x4 s4[4];
  const f32x4 z = {0.f, 0.f, 0.f, 0.f};
#pragma unroll
  for (int f = 0; f < 4; ++f) s4[f] = z;
#pragma unroll
  for (int s = 0; s < 2; ++s) {
    const int cb = s * 64 + lg * 16;
#pragma unroll
    for (int f = 0; f < 4; ++f) {
      const int row = lr + 16 * f;
      const int byt = row * 128 + (cb ^ ((row & 7) << 4));
      const short8 bh8 = *(const short8*)(khp + byt);
      const short8 bl8 = *(const short8*)(klp + byt);
      s4[f] = __builtin_amdgcn_mfma_f32_16x16x32_bf16(qh[s], bh8, s4[f], 0, 0, 0);
      s4[f] = __builtin_amdgcn_mfma_f32_16x16x32_bf16(ql[s], bh8, s4[f], 0, 0, 0);
      s4[f] = __builtin_amdgcn_mfma_f32_16x16x32_bf16(qh[s], bl8, s4[f], 0, 0, 0);
    }
  }
  if (diag) {
#pragma unroll
    for (int f = 0; f < 4; ++f) {
      const int kg = 16 * f + lr;
#pragma unroll
      for (int r = 0; r < 4; ++r) {
        const int qg = w * 16 + lg * 4 + r;
        if (kg > qg) s4[f][r] = -1e30f;
      }
    }
  }
  float mc[4], resc[4], ps[4];
#pragma unroll
  for (int r = 0; r < 4; ++r)
    mc[r] = fmaxf(fmaxf(s4[0][r], s4[1][r]), fmaxf(s4[2][r], s4[3][r]));
#pragma unroll
  for (int d = 1; d <= 8; d <<= 1)
#pragma unroll
    for (int r = 0; r < 4; ++r) mc[r] = fmaxf(mc[r], __shfl_xor(mc[r], d));
#pragma unroll
  for (int r = 0; r < 4; ++r) {
    const float mn = fmaxf(st.m[r], mc[r]);
    resc[r] = __expf(st.m[r] - mn);
    st.m[r] = mn;
    ps[r] = 0.f;
  }
#pragma unroll
  for (int f = 0; f < 4; ++f)
#pragma unroll
    for (int r = 0; r < 4; ++r) {
      const float p = __expf(s4[f][r] - st.m[r]);
      s4[f][r] = p;
      ps[r] += p;
    }
#pragma unroll
  for (int d = 1; d <= 8; d <<= 1)
#pragma unroll
    for (int r = 0; r < 4; ++r) ps[r] += __shfl_xor(ps[r], d);
#pragma unroll
  for (int r = 0; r < 4; ++r) st.l[r] = st.l[r] * resc[r] + ps[r];
#pragma unroll
  for (int n = 0; n < 4; ++n)
#pragma unroll
    for (int r = 0; r < 4; ++r) st.O[n][r] *= resc[r];
#pragma unroll
  for (int f = 0; f < 4; ++f)
#pragma unroll
    for (int r = 0; r < 4; ++r) {
      const int q = lg * 4 + r;
      *(short*)(pp + q * 128 + (((lr + 16 * f) * 2) ^ ((q & 7) << 4))) = (short)f2bf(s4[f][r]);
    }
#pragma unroll
  for (int s = 0; s < 2; ++s) {
    const int cb = s * 64 + lg * 16;
    const short8 pa = *(const short8*)(pp + lr * 128 + (cb ^ ((lr & 7) << 4)));
#pragma unroll
    for (int n = 0; n < 4; ++n) {
      const int d = lr + 16 * n;
      const short8 vb = *(const short8*)(vTp + d * 128 + (cb ^ ((d & 7) << 4)));
      st.O[n] = __builtin_amdgcn_mfma_f32_16x16x32_bf16(pa, vb, st.O[n], 0, 0, 0);
    }
  }
}

__device__ __forceinline__ void load_q(const float* base, int qt, int h,
                                       int w, int lg, int lr,
                                       short8* qh, short8* ql) {
  const float* qrow = base + (size_t)(qt * 64 + w * 16 + lr) * N_QKV + (h << 6);
#pragma unroll
  for (int s = 0; s < 2; ++s) {
    const float4 a0 = *(const float4*)(qrow + s * 32 + lg * 8);
    const float4 a1 = *(const float4*)(qrow + s * 32 + lg * 8 + 4);
    const float xv[8] = {a0.x, a0.y, a0.z, a0.w, a1.x, a1.y, a1.z, a1.w};
#pragma unroll
    for (int j = 0; j < 8; ++j) {
      const float xs = xv[j] * 0.125f;       // fold 1/sqrt(64)
      const unsigned short hs = f2bf(xs);
      qh[s][j] = (short)hs;
      ql[s][j] = (short)f2bf(xs - bf2f(hs));
    }
  }
}

__device__ __forceinline__ void store_o(ushort_t* oh, TS& st,
                                        int b, int qt, int h,
                                        int w, int lg, int lr) {
  float inv[4];
#pragma unroll
  for (int r = 0; r < 4; ++r) inv[r] = 1.f / st.l[r];
  const size_t ob = (size_t)(b * T_SEQ + qt * 64 + w * 16 + lg * 4) * C_DIM + (h << 6) + lr;
#pragma unroll
  for (int r = 0; r < 4; ++r)
#pragma unroll
    for (int n = 0; n < 4; ++n)
      oh[ob + (size_t)r * C_DIM + 16 * n] = f2bf(st.O[n][r] * inv[r]);
}

__global__ __launch_bounds__(256, 5) void attn2_k(const float* __restrict__ qkv,
                                                  const char* __restrict__ img,
                                                  ushort_t* __restrict__ oh) {
  __shared__ __align__(16) char smem[32768];   // img 24K | P 4x2K
  const int tid  = threadIdx.x;
  const int lane = tid & 63;
  const int w    = tid >> 6;
  const int lg   = lane >> 4;
  const int lr   = lane & 15;
  char* const pp = smem + 24576 + (w << 11);

  // gg in low bits -> all 16 p-blocks of one (b,h) land on one XCD (L2-hot img)
  const int bx = blockIdx.x;
  const int p  = (bx >> 3) & 15;
  const int gg = ((bx >> 7) << 3) | (bx & 7);
  const int h  = gg & 15, b = gg >> 4;
  const int qtA = p, qtB = 31 - p;

  const float* base = qkv + (size_t)b * T_SEQ * N_QKV;
  const char* img_gg = img + (size_t)gg * 32 * 24576;

  short8 qhA[2], qlA[2], qhB[2], qlB[2];
  load_q(base, qtA, h, w, lg, lr, qhA, qlA);
  load_q(base, qtB, h, w, lg, lr, qhB, qlB);

  TS stA, stB;
#pragma unroll
  for (int n = 0; n < 4; ++n) {
    const f32x4 z = {0.f, 0.f, 0.f, 0.f};
    stA.O[n] = z; stB.O[n] = z;
    stA.m[n] = -1e30f; stB.m[n] = -1e30f;
    stA.l[n] = 0.f; stB.l[n] = 0.f;
  }

  for (int c = 0; c <= qtB; ++c) {
    const char* src = img_gg + (size_t)c * 24576;
#pragma unroll
    for (int i = 0; i < 6; ++i)
      gll16(src + i * 4096 + tid * 16, smem + i * 4096 + tid * 16);
    __syncthreads();                     // drains vmcnt -> image ready
    tile_step(smem, smem + 8192, smem + 16384, pp, qhB, qlB, stB, c == qtB, w, lg, lr);
    if (c <= qtA)
      tile_step(smem, smem + 8192, smem + 16384, pp, qhA, qlA, stA, c == qtA, w, lg, lr);
    __syncthreads();                     // all waves done before next overwrite
  }

  store_o(oh, stA, b, qtA, h, w, lg, lr);
  store_o(oh, stB, b, qtB, h, w, lg, lr);
}

// ---------------- launch ----------------------------------------------------
extern "C" void kernel_launch(void* const* d_in, const int* in_sizes, int n_in,
                              void* d_out, int out_size, void* d_ws, size_t ws_size,
                              hipStream_t stream) {
  const float* x      = (const float*)d_in[0];   // [4096][1024]
  const float* w_qkv  = (const float*)d_in[1];   // [3072][1024]
  const float* w_out  = (const float*)d_in[2];   // [1024][1024]
  float* out = (float*)d_out;                    // [4096][1024]

  // layout (img aliases wt_qkv, which is dead after gemm1; stream-ordered)
  char* pch = (char*)d_ws;
  ushort_t* wt_out = (ushort_t*)pch;  pch += (size_t)C_DIM * C_DIM * 2;    // 2MB
  ushort_t* xh     = (ushort_t*)pch;  pch += (size_t)M_ROWS * C_DIM * 2;   // 8MB
  ushort_t* xl     = (ushort_t*)pch;  pch += (size_t)M_ROWS * C_DIM * 2;   // 8MB
  float*    qkv    = (float*)pch;     pch += (size_t)M_ROWS * N_QKV * 4;   // 48MB
  ushort_t* wt_qkv = (ushort_t*)pch;                                       // 6MB..
  char*     img    = pch;             pch += (size_t)1024 * 24576;         // 25.2MB
  float*    part   = (float*)pch;     pch += 512 * 4;
  float*    scales = (float*)pch;
  ushort_t* ah = xh;   // x hi dead after gemm1 -> reuse for attn output

  hipLaunchKernelGGL(abs_partial_k, dim3(256), dim3(256), 0, stream,
                     w_qkv, N_QKV * C_DIM, part);
  hipLaunchKernelGGL(abs_partial_k, dim3(256), dim3(256), 0, stream,
                     w_out, C_DIM * C_DIM, part + 256);
  hipLaunchKernelGGL(finalize_scales_k, dim3(2), dim3(256), 0, stream, part, scales);

  hipLaunchKernelGGL(ternarize_k, dim3((N_QKV * C_DIM) / 256), dim3(256), 0, stream,
                     w_qkv, wt_qkv, N_QKV * C_DIM, scales, 0);
  hipLaunchKernelGGL(ternarize_k, dim3((C_DIM * C_DIM) / 256), dim3(256), 0, stream,
                     w_out, wt_out, C_DIM * C_DIM, scales, 1);

  hipLaunchKernelGGL(split_hl_k, dim3((M_ROWS * C_DIM / 4) / 256), dim3(256), 0, stream,
                     x, xh, xl, M_ROWS * C_DIM / 4);

  // qkv = (xh+xl) @ wt_qkv^T
  hipLaunchKernelGGL(gemm_bf16_hl, dim3(N_QKV / 128, M_ROWS / 128), dim3(256), 0, stream,
                     xh, xl, wt_qkv, qkv, N_QKV, C_DIM);

  // K/V chunk images (overwrites wt_qkv region — dead now)
  hipLaunchKernelGGL(prep_kv_k, dim3(1024), dim3(256), 0, stream, qkv, img);

  // attention -> bf16 (single precision stream; out-proj not tie-sensitive)
  hipLaunchKernelGGL(attn2_k, dim3(512), dim3(256), 0, stream, qkv, img, ah);

  // out = ah @ wt_out^T
  hipLaunchKernelGGL(gemm_bf16, dim3(C_DIM / 128, M_ROWS / 128), dim3(256), 0, stream,
                     ah, wt_out, out, C_DIM, C_DIM);
}

// Round 7
// 249.352 us; speedup vs baseline: 2.2922x; 2.2922x over previous
//
#include <hip/hip_runtime.h>
#include <math.h>

#define T_SEQ 2048
#define C_DIM 1024
#define NHEAD 16
#define HDIM 64
#define M_ROWS 4096   // B*T
#define N_QKV 3072    // 3*C

typedef __attribute__((ext_vector_type(8))) short short8;   // 8 bf16 (4 VGPR)
typedef __attribute__((ext_vector_type(4))) float f32x4;    // MFMA C/D
typedef unsigned short ushort_t;

__device__ inline unsigned short f2bf(float x) {            // RNE f32->bf16
  union { float f; unsigned u; } v; v.f = x;
  unsigned r = v.u + 0x7FFF + ((v.u >> 16) & 1);
  return (unsigned short)(r >> 16);
}
__device__ inline float bf2f(unsigned short h) {
  union { unsigned u; float f; } v; v.u = ((unsigned)h) << 16; return v.f;
}

// async global->LDS, 16B per lane; LDS dest = wave-uniform base + lane*16
__device__ __forceinline__ void gll16(const char* g, char* l) {
  __builtin_amdgcn_global_load_lds(
      (const __attribute__((address_space(1))) unsigned*)g,
      (__attribute__((address_space(3))) unsigned*)l, 16, 0, 0);
}

// ---------------- abs-mean scale (deterministic 2-stage reduction) ----------
__global__ __launch_bounds__(256) void abs_partial_k(const float* __restrict__ w,
                                                     int n, float* __restrict__ part) {
  __shared__ float red[256];
  float s = 0.f;
  for (int i = blockIdx.x * 256 + threadIdx.x; i < n; i += 256 * 256)
    s += fabsf(w[i]);
  red[threadIdx.x] = s;
  __syncthreads();
  for (int st = 128; st > 0; st >>= 1) {
    if ((int)threadIdx.x < st) red[threadIdx.x] += red[threadIdx.x + st];
    __syncthreads();
  }
  if (threadIdx.x == 0) part[blockIdx.x] = red[0];
}

__global__ __launch_bounds__(256) void finalize_scales_k(const float* __restrict__ part,
                                                         float* __restrict__ scales) {
  __shared__ float red[256];
  red[threadIdx.x] = part[blockIdx.x * 256 + threadIdx.x];
  __syncthreads();
  for (int st = 128; st > 0; st >>= 1) {
    if ((int)threadIdx.x < st) red[threadIdx.x] += red[threadIdx.x + st];
    __syncthreads();
  }
  if (threadIdx.x == 0) {
    float n = (blockIdx.x == 0) ? (float)(N_QKV * C_DIM) : (float)(C_DIM * C_DIM);
    scales[blockIdx.x] = fmaxf(red[0] / n, 1e-8f);
  }
}

// ---------------- ternarize -> bf16 (exact: {-1,0,1}) -----------------------
__global__ __launch_bounds__(256) void ternarize_k(const float* __restrict__ w,
                                                   ushort_t* __restrict__ wt, int n,
                                                   const float* __restrict__ scales,
                                                   int which) {
  int i = blockIdx.x * 256 + threadIdx.x;
  if (i < n) {
    float s = scales[which];
    float t = rintf(w[i] / s);           // round-half-even matches jnp.round
    wt[i] = f2bf(fminf(1.f, fmaxf(-1.f, t)));
  }
}

// ---------------- fp32 -> bf16 hi/lo split ----------------------------------
__global__ __launch_bounds__(256) void split_hl_k(const float* __restrict__ in,
                                                  ushort_t* __restrict__ hi,
                                                  ushort_t* __restrict__ lo, int n4) {
  int i = blockIdx.x * 256 + threadIdx.x;
  if (i < n4) {
    const float4 v = ((const float4*)in)[i];
    const float vv[4] = {v.x, v.y, v.z, v.w};
    ushort_t hh[4], ll[4];
#pragma unroll
    for (int j = 0; j < 4; ++j) {
      hh[j] = f2bf(vv[j]);
      ll[j] = f2bf(vv[j] - bf2f(hh[j]));
    }
    ((ushort4*)hi)[i] = make_ushort4(hh[0], hh[1], hh[2], hh[3]);
    ((ushort4*)lo)[i] = make_ushort4(ll[0], ll[1], ll[2], ll[3]);
  }
}

// ---------------- bf16 MFMA GEMM, A split hi/lo (qkv projection) ------------
// C[m][n] = sum_k (Ah+Al)[m][k] * Bw[n][k]; tile 128x128, BK=64, 4 waves 2x2.
// LDS rows 128B, XOR-swizzled (T2) -> conflict-free ds_read_b128.
__global__ __launch_bounds__(256) void gemm_bf16_hl(const ushort_t* __restrict__ Ah,
                                                    const ushort_t* __restrict__ Al,
                                                    const ushort_t* __restrict__ Bw,
                                                    float* __restrict__ C,
                                                    int Nd, int Kd) {
  __shared__ __align__(16) ushort_t Ash[128 * 64];
  __shared__ __align__(16) ushort_t Asl[128 * 64];
  __shared__ __align__(16) ushort_t Bs[128 * 64];
  const int tid = threadIdx.x;
  const int bm = blockIdx.y << 7, bn = blockIdx.x << 7;
  const int w = tid >> 6, lane = tid & 63;
  const int wm = (w >> 1) << 6, wn = (w & 1) << 6;
  const int fr = lane & 15, fc = lane >> 4;
  const int srow = tid >> 1;                 // staging row 0..127
  const int sv0 = (tid & 1) << 2;            // 16B-slot base: 0 or 4
  const int swz = (srow & 7) << 4;
  const size_t arow = (size_t)(bm + srow) * Kd;
  const size_t brow = (size_t)(bn + srow) * Kd;
  int wb[4];
#pragma unroll
  for (int j = 0; j < 4; ++j) wb[j] = srow * 128 + (((sv0 + j) << 4) ^ swz);

  f32x4 acc[4][4];
  const f32x4 z = {0.f, 0.f, 0.f, 0.f};
#pragma unroll
  for (int i = 0; i < 4; ++i)
#pragma unroll
    for (int j = 0; j < 4; ++j) acc[i][j] = z;

  for (int k0 = 0; k0 < Kd; k0 += 64) {
    const int gcol = k0 + (sv0 << 3);        // elem col: k0 + (tid&1)*32
    short8 sa[4], sl[4], sb[4];
#pragma unroll
    for (int j = 0; j < 4; ++j) {
      sa[j] = *(const short8*)(Ah + arow + gcol + j * 8);
      sl[j] = *(const short8*)(Al + arow + gcol + j * 8);
      sb[j] = *(const short8*)(Bw + brow + gcol + j * 8);
    }
    __syncthreads();
#pragma unroll
    for (int j = 0; j < 4; ++j) {
      *(short8*)((char*)Ash + wb[j]) = sa[j];
      *(short8*)((char*)Asl + wb[j]) = sl[j];
      *(short8*)((char*)Bs  + wb[j]) = sb[j];
    }
    __syncthreads();
#pragma unroll
    for (int ks = 0; ks < 2; ++ks) {
      short8 af[4], lf[4], bf[4];
#pragma unroll
      for (int i = 0; i < 4; ++i) {
        const int ra = wm + i * 16 + fr;
        af[i] = *(const short8*)((const char*)Ash + ra * 128 + ((ks * 64 + fc * 16) ^ ((ra & 7) << 4)));
        lf[i] = *(const short8*)((const char*)Asl + ra * 128 + ((ks * 64 + fc * 16) ^ ((ra & 7) << 4)));
        const int rb = wn + i * 16 + fr;
        bf[i] = *(const short8*)((const char*)Bs + rb * 128 + ((ks * 64 + fc * 16) ^ ((rb & 7) << 4)));
      }
#pragma unroll
      for (int i = 0; i < 4; ++i)
#pragma unroll
        for (int j = 0; j < 4; ++j) {
          acc[i][j] = __builtin_amdgcn_mfma_f32_16x16x32_bf16(af[i], bf[j], acc[i][j], 0, 0, 0);
          acc[i][j] = __builtin_amdgcn_mfma_f32_16x16x32_bf16(lf[i], bf[j], acc[i][j], 0, 0, 0);
        }
    }
  }
#pragma unroll
  for (int i = 0; i < 4; ++i)
#pragma unroll
    for (int j = 0; j < 4; ++j) {
      float* cp = C + (size_t)(bm + wm + i * 16 + fc * 4) * Nd + bn + wn + j * 16 + fr;
#pragma unroll
      for (int r = 0; r < 4; ++r) cp[(size_t)r * Nd] = acc[i][j][r];
    }
}

// ---------------- bf16 MFMA GEMM, single-pass A (out projection) ------------
__global__ __launch_bounds__(256) void gemm_bf16(const ushort_t* __restrict__ A,
                                                 const ushort_t* __restrict__ Bw,
                                                 float* __restrict__ C,
                                                 int Nd, int Kd) {
  __shared__ __align__(16) ushort_t Ash[128 * 64];
  __shared__ __align__(16) ushort_t Bs[128 * 64];
  const int tid = threadIdx.x;
  const int bm = blockIdx.y << 7, bn = blockIdx.x << 7;
  const int w = tid >> 6, lane = tid & 63;
  const int wm = (w >> 1) << 6, wn = (w & 1) << 6;
  const int fr = lane & 15, fc = lane >> 4;
  const int srow = tid >> 1;
  const int sv0 = (tid & 1) << 2;
  const int swz = (srow & 7) << 4;
  const size_t arow = (size_t)(bm + srow) * Kd;
  const size_t brow = (size_t)(bn + srow) * Kd;
  int wb[4];
#pragma unroll
  for (int j = 0; j < 4; ++j) wb[j] = srow * 128 + (((sv0 + j) << 4) ^ swz);

  f32x4 acc[4][4];
  const f32x4 z = {0.f, 0.f, 0.f, 0.f};
#pragma unroll
  for (int i = 0; i < 4; ++i)
#pragma unroll
    for (int j = 0; j < 4; ++j) acc[i][j] = z;

  for (int k0 = 0; k0 < Kd; k0 += 64) {
    const int gcol = k0 + (sv0 << 3);
    short8 sa[4], sb[4];
#pragma unroll
    for (int j = 0; j < 4; ++j) {
      sa[j] = *(const short8*)(A + arow + gcol + j * 8);
      sb[j] = *(const short8*)(Bw + brow + gcol + j * 8);
    }
    __syncthreads();
#pragma unroll
    for (int j = 0; j < 4; ++j) {
      *(short8*)((char*)Ash + wb[j]) = sa[j];
      *(short8*)((char*)Bs  + wb[j]) = sb[j];
    }
    __syncthreads();
#pragma unroll
    for (int ks = 0; ks < 2; ++ks) {
      short8 af[4], bf[4];
#pragma unroll
      for (int i = 0; i < 4; ++i) {
        const int ra = wm + i * 16 + fr;
        af[i] = *(const short8*)((const char*)Ash + ra * 128 + ((ks * 64 + fc * 16) ^ ((ra & 7) << 4)));
        const int rb = wn + i * 16 + fr;
        bf[i] = *(const short8*)((const char*)Bs + rb * 128 + ((ks * 64 + fc * 16) ^ ((rb & 7) << 4)));
      }
#pragma unroll
      for (int i = 0; i < 4; ++i)
#pragma unroll
        for (int j = 0; j < 4; ++j)
          acc[i][j] = __builtin_amdgcn_mfma_f32_16x16x32_bf16(af[i], bf[j], acc[i][j], 0, 0, 0);
    }
  }
#pragma unroll
  for (int i = 0; i < 4; ++i)
#pragma unroll
    for (int j = 0; j < 4; ++j) {
      float* cp = C + (size_t)(bm + wm + i * 16 + fc * 4) * Nd + bn + wn + j * 16 + fr;
#pragma unroll
      for (int r = 0; r < 4; ++r) cp[(size_t)r * Nd] = acc[i][j][r];
    }
}

// ---------------- prep_kv: per-(b,h,chunk) swizzled LDS images --------------
__global__ __launch_bounds__(256) void prep_kv_k(const float* __restrict__ qkv,
                                                 char* __restrict__ img) {
  __shared__ __align__(16) char sm[24576];
  const int tid = threadIdx.x;
  const int c = blockIdx.x & 31, gg = blockIdx.x >> 5;
  const int h = gg & 15, b = gg >> 4;
  const int key = tid >> 2, dg = tid & 3;
  const float* kp = qkv + (size_t)b * T_SEQ * N_QKV +
                    (size_t)(c * 64 + key) * N_QKV + C_DIM + (h << 6) + dg * 16;
  const float4 k0 = *(const float4*)(kp + 0);
  const float4 k1 = *(const float4*)(kp + 4);
  const float4 k2 = *(const float4*)(kp + 8);
  const float4 k3 = *(const float4*)(kp + 12);
  const float4 v0 = *(const float4*)(kp + C_DIM + 0);
  const float4 v1 = *(const float4*)(kp + C_DIM + 4);
  const float4 v2 = *(const float4*)(kp + C_DIM + 8);
  const float4 v3 = *(const float4*)(kp + C_DIM + 12);
  const float kv[16] = {k0.x,k0.y,k0.z,k0.w, k1.x,k1.y,k1.z,k1.w,
                        k2.x,k2.y,k2.z,k2.w, k3.x,k3.y,k3.z,k3.w};
  const float vv[16] = {v0.x,v0.y,v0.z,v0.w, v1.x,v1.y,v1.z,v1.w,
                        v2.x,v2.y,v2.z,v2.w, v3.x,v3.y,v3.z,v3.w};
  short8 khi0, khi1, klo0, klo1;
#pragma unroll
  for (int j = 0; j < 8; ++j) {
    const float x0 = kv[j], x1 = kv[8 + j];
    const unsigned short h0 = f2bf(x0), h1 = f2bf(x1);
    khi0[j] = (short)h0; khi1[j] = (short)h1;
    klo0[j] = (short)f2bf(x0 - bf2f(h0));
    klo1[j] = (short)f2bf(x1 - bf2f(h1));
  }
  const int sw = (key & 7) << 4;
  const int b0 = key * 128 + ((dg * 32) ^ sw);
  const int b1 = key * 128 + ((dg * 32 + 16) ^ sw);
  *(short8*)(sm + b0) = khi0;        *(short8*)(sm + b1) = khi1;
  *(short8*)(sm + 8192 + b0) = klo0; *(short8*)(sm + 8192 + b1) = klo1;
#pragma unroll
  for (int i = 0; i < 16; ++i) {
    const int d = dg * 16 + i;
    *(short*)(sm + 16384 + d * 128 + ((key * 2) ^ ((d & 7) << 4))) = (short)f2bf(vv[i]);
  }
  __syncthreads();
  int4* dst = (int4*)(img + (size_t)blockIdx.x * 24576);
  const int4* src = (const int4*)sm;
#pragma unroll
  for (int i = 0; i < 6; ++i) dst[i * 256 + tid] = src[i * 256 + tid];
}

// ---------------- paired-tile MFMA flash attention --------------------------
// Single-buffered 24KB chunk image + 8KB P = 32KB LDS; NO min-wave coercion
// (R6 lesson: forcing 5 waves/EU spilled TS state -> 1.8GB scratch traffic).
// VGPR ~92 + LDS 32KB both allow 5 blocks/CU naturally.
struct TS { f32x4 O[4]; float m[4]; float l[4]; };

__device__ __forceinline__ void tile_step(const char* khp, const char* klp,
                                          const char* vTp, char* pp,
                                          const short8* qh, const short8* ql,
                                          TS& st, const bool diag,
                                          const int w, const int lg, const int lr) {
  f32x4 s4[4];
  const f32x4 z = {0.f, 0.f, 0.f, 0.f};
#pragma unroll
  for (int f = 0; f < 4; ++f) s4[f] = z;
#pragma unroll
  for (int s = 0; s < 2; ++s) {
    const int cb = s * 64 + lg * 16;
#pragma unroll
    for (int f = 0; f < 4; ++f) {
      const int row = lr + 16 * f;
      const int byt = row * 128 + (cb ^ ((row & 7) << 4));
      const short8 bh8 = *(const short8*)(khp + byt);
      const short8 bl8 = *(const short8*)(klp + byt);
      s4[f] = __builtin_amdgcn_mfma_f32_16x16x32_bf16(qh[s], bh8, s4[f], 0, 0, 0);
      s4[f] = __builtin_amdgcn_mfma_f32_16x16x32_bf16(ql[s], bh8, s4[f], 0, 0, 0);
      s4[f] = __builtin_amdgcn_mfma_f32_16x16x32_bf16(qh[s], bl8, s4[f], 0, 0, 0);
    }
  }
  if (diag) {
#pragma unroll
    for (int f = 0; f < 4; ++f) {
      const int kg = 16 * f + lr;
#pragma unroll
      for (int r = 0; r < 4; ++r) {
        const int qg = w * 16 + lg * 4 + r;
        if (kg > qg) s4[f][r] = -1e30f;
      }
    }
  }
  float mc[4], resc[4], ps[4];
#pragma unroll
  for (int r = 0; r < 4; ++r)
    mc[r] = fmaxf(fmaxf(s4[0][r], s4[1][r]), fmaxf(s4[2][r], s4[3][r]));
#pragma unroll
  for (int d = 1; d <= 8; d <<= 1)
#pragma unroll
    for (int r = 0; r < 4; ++r) mc[r] = fmaxf(mc[r], __shfl_xor(mc[r], d));
#pragma unroll
  for (int r = 0; r < 4; ++r) {
    const float mn = fmaxf(st.m[r], mc[r]);
    resc[r] = __expf(st.m[r] - mn);
    st.m[r] = mn;
    ps[r] = 0.f;
  }
#pragma unroll
  for (int f = 0; f < 4; ++f)
#pragma unroll
    for (int r = 0; r < 4; ++r) {
      const float p = __expf(s4[f][r] - st.m[r]);
      s4[f][r] = p;
      ps[r] += p;
    }
#pragma unroll
  for (int d = 1; d <= 8; d <<= 1)
#pragma unroll
    for (int r = 0; r < 4; ++r) ps[r] += __shfl_xor(ps[r], d);
#pragma unroll
  for (int r = 0; r < 4; ++r) st.l[r] = st.l[r] * resc[r] + ps[r];
#pragma unroll
  for (int n = 0; n < 4; ++n)
#pragma unroll
    for (int r = 0; r < 4; ++r) st.O[n][r] *= resc[r];
#pragma unroll
  for (int f = 0; f < 4; ++f)
#pragma unroll
    for (int r = 0; r < 4; ++r) {
      const int q = lg * 4 + r;
      *(short*)(pp + q * 128 + (((lr + 16 * f) * 2) ^ ((q & 7) << 4))) = (short)f2bf(s4[f][r]);
    }
#pragma unroll
  for (int s = 0; s < 2; ++s) {
    const int cb = s * 64 + lg * 16;
    const short8 pa = *(const short8*)(pp + lr * 128 + (cb ^ ((lr & 7) << 4)));
#pragma unroll
    for (int n = 0; n < 4; ++n) {
      const int d = lr + 16 * n;
      const short8 vb = *(const short8*)(vTp + d * 128 + (cb ^ ((d & 7) << 4)));
      st.O[n] = __builtin_amdgcn_mfma_f32_16x16x32_bf16(pa, vb, st.O[n], 0, 0, 0);
    }
  }
}

__device__ __forceinline__ void load_q(const float* base, int qt, int h,
                                       int w, int lg, int lr,
                                       short8* qh, short8* ql) {
  const float* qrow = base + (size_t)(qt * 64 + w * 16 + lr) * N_QKV + (h << 6);
#pragma unroll
  for (int s = 0; s < 2; ++s) {
    const float4 a0 = *(const float4*)(qrow + s * 32 + lg * 8);
    const float4 a1 = *(const float4*)(qrow + s * 32 + lg * 8 + 4);
    const float xv[8] = {a0.x, a0.y, a0.z, a0.w, a1.x, a1.y, a1.z, a1.w};
#pragma unroll
    for (int j = 0; j < 8; ++j) {
      const float xs = xv[j] * 0.125f;       // fold 1/sqrt(64)
      const unsigned short hs = f2bf(xs);
      qh[s][j] = (short)hs;
      ql[s][j] = (short)f2bf(xs - bf2f(hs));
    }
  }
}

__device__ __forceinline__ void store_o(ushort_t* oh, TS& st,
                                        int b, int qt, int h,
                                        int w, int lg, int lr) {
  float inv[4];
#pragma unroll
  for (int r = 0; r < 4; ++r) inv[r] = 1.f / st.l[r];
  const size_t ob = (size_t)(b * T_SEQ + qt * 64 + w * 16 + lg * 4) * C_DIM + (h << 6) + lr;
#pragma unroll
  for (int r = 0; r < 4; ++r)
#pragma unroll
    for (int n = 0; n < 4; ++n)
      oh[ob + (size_t)r * C_DIM + 16 * n] = f2bf(st.O[n][r] * inv[r]);
}

__global__ __launch_bounds__(256) void attn2_k(const float* __restrict__ qkv,
                                               const char* __restrict__ img,
                                               ushort_t* __restrict__ oh) {
  __shared__ __align__(16) char smem[32768];   // img 24K | P 4x2K
  const int tid  = threadIdx.x;
  const int lane = tid & 63;
  const int w    = tid >> 6;
  const int lg   = lane >> 4;
  const int lr   = lane & 15;
  char* const pp = smem + 24576 + (w << 11);

  // gg in low bits -> all 16 p-blocks of one (b,h) land on one XCD (L2-hot img)
  const int bx = blockIdx.x;
  const int p  = (bx >> 3) & 15;
  const int gg = ((bx >> 7) << 3) | (bx & 7);
  const int h  = gg & 15, b = gg >> 4;
  const int qtA = p, qtB = 31 - p;

  const float* base = qkv + (size_t)b * T_SEQ * N_QKV;
  const char* img_gg = img + (size_t)gg * 32 * 24576;

  short8 qhA[2], qlA[2], qhB[2], qlB[2];
  load_q(base, qtA, h, w, lg, lr, qhA, qlA);
  load_q(base, qtB, h, w, lg, lr, qhB, qlB);

  TS stA, stB;
#pragma unroll
  for (int n = 0; n < 4; ++n) {
    const f32x4 z = {0.f, 0.f, 0.f, 0.f};
    stA.O[n] = z; stB.O[n] = z;
    stA.m[n] = -1e30f; stB.m[n] = -1e30f;
    stA.l[n] = 0.f; stB.l[n] = 0.f;
  }

  for (int c = 0; c <= qtB; ++c) {
    const char* src = img_gg + (size_t)c * 24576;
#pragma unroll
    for (int i = 0; i < 6; ++i)
      gll16(src + i * 4096 + tid * 16, smem + i * 4096 + tid * 16);
    __syncthreads();                     // drains vmcnt -> image ready
    tile_step(smem, smem + 8192, smem + 16384, pp, qhB, qlB, stB, c == qtB, w, lg, lr);
    if (c <= qtA)
      tile_step(smem, smem + 8192, smem + 16384, pp, qhA, qlA, stA, c == qtA, w, lg, lr);
    __syncthreads();                     // all waves done before next overwrite
  }

  store_o(oh, stA, b, qtA, h, w, lg, lr);
  store_o(oh, stB, b, qtB, h, w, lg, lr);
}

// ---------------- launch ----------------------------------------------------
extern "C" void kernel_launch(void* const* d_in, const int* in_sizes, int n_in,
                              void* d_out, int out_size, void* d_ws, size_t ws_size,
                              hipStream_t stream) {
  const float* x      = (const float*)d_in[0];   // [4096][1024]
  const float* w_qkv  = (const float*)d_in[1];   // [3072][1024]
  const float* w_out  = (const float*)d_in[2];   // [1024][1024]
  float* out = (float*)d_out;                    // [4096][1024]

  // layout (img aliases wt_qkv, which is dead after gemm1; stream-ordered)
  char* pch = (char*)d_ws;
  ushort_t* wt_out = (ushort_t*)pch;  pch += (size_t)C_DIM * C_DIM * 2;    // 2MB
  ushort_t* xh     = (ushort_t*)pch;  pch += (size_t)M_ROWS * C_DIM * 2;   // 8MB
  ushort_t* xl     = (ushort_t*)pch;  pch += (size_t)M_ROWS * C_DIM * 2;   // 8MB
  float*    qkv    = (float*)pch;     pch += (size_t)M_ROWS * N_QKV * 4;   // 48MB
  ushort_t* wt_qkv = (ushort_t*)pch;                                       // 6MB..
  char*     img    = pch;             pch += (size_t)1024 * 24576;         // 25.2MB
  float*    part   = (float*)pch;     pch += 512 * 4;
  float*    scales = (float*)pch;
  ushort_t* ah = xh;   // x hi dead after gemm1 -> reuse for attn output

  hipLaunchKernelGGL(abs_partial_k, dim3(256), dim3(256), 0, stream,
                     w_qkv, N_QKV * C_DIM, part);
  hipLaunchKernelGGL(abs_partial_k, dim3(256), dim3(256), 0, stream,
                     w_out, C_DIM * C_DIM, part + 256);
  hipLaunchKernelGGL(finalize_scales_k, dim3(2), dim3(256), 0, stream, part, scales);

  hipLaunchKernelGGL(ternarize_k, dim3((N_QKV * C_DIM) / 256), dim3(256), 0, stream,
                     w_qkv, wt_qkv, N_QKV * C_DIM, scales, 0);
  hipLaunchKernelGGL(ternarize_k, dim3((C_DIM * C_DIM) / 256), dim3(256), 0, stream,
                     w_out, wt_out, C_DIM * C_DIM, scales, 1);

  hipLaunchKernelGGL(split_hl_k, dim3((M_ROWS * C_DIM / 4) / 256), dim3(256), 0, stream,
                     x, xh, xl, M_ROWS * C_DIM / 4);

  // qkv = (xh+xl) @ wt_qkv^T
  hipLaunchKernelGGL(gemm_bf16_hl, dim3(N_QKV / 128, M_ROWS / 128), dim3(256), 0, stream,
                     xh, xl, wt_qkv, qkv, N_QKV, C_DIM);

  // K/V chunk images (overwrites wt_qkv region — dead now)
  hipLaunchKernelGGL(prep_kv_k, dim3(1024), dim3(256), 0, stream, qkv, img);

  // attention -> bf16 (single precision stream; out-proj not tie-sensitive)
  hipLaunchKernelGGL(attn2_k, dim3(512), dim3(256), 0, stream, qkv, img, ah);

  // out = ah @ wt_out^T
  hipLaunchKernelGGL(gemm_bf16, dim3(C_DIM / 128, M_ROWS / 128), dim3(256), 0, stream,
                     ah, wt_out, out, C_DIM, C_DIM);
}

// Round 8
// 199.209 us; speedup vs baseline: 2.8692x; 1.2517x over previous
//
#include <hip/hip_runtime.h>
#include <math.h>

#define T_SEQ 2048
#define C_DIM 1024
#define NHEAD 16
#define HDIM 64
#define M_ROWS 4096   // B*T
#define N_QKV 3072    // 3*C

typedef __attribute__((ext_vector_type(8))) short short8;   // 8 bf16 (4 VGPR)
typedef __attribute__((ext_vector_type(4))) float f32x4;    // MFMA C/D
typedef unsigned short ushort_t;

__device__ inline unsigned short f2bf(float x) {            // RNE f32->bf16
  union { float f; unsigned u; } v; v.f = x;
  unsigned r = v.u + 0x7FFF + ((v.u >> 16) & 1);
  return (unsigned short)(r >> 16);
}
__device__ inline float bf2f(unsigned short h) {
  union { unsigned u; float f; } v; v.u = ((unsigned)h) << 16; return v.f;
}

// async global->LDS, 16B per lane; LDS dest = wave-uniform base + lane*16
__device__ __forceinline__ void gll16(const char* g, char* l) {
  __builtin_amdgcn_global_load_lds(
      (const __attribute__((address_space(1))) unsigned*)g,
      (__attribute__((address_space(3))) unsigned*)l, 16, 0, 0);
}

// ---------------- abs-mean scale (deterministic 2-stage reduction) ----------
__global__ __launch_bounds__(256) void abs_partial_k(const float* __restrict__ w,
                                                     int n, float* __restrict__ part) {
  __shared__ float red[256];
  float s = 0.f;
  for (int i = blockIdx.x * 256 + threadIdx.x; i < n; i += 256 * 256)
    s += fabsf(w[i]);
  red[threadIdx.x] = s;
  __syncthreads();
  for (int st = 128; st > 0; st >>= 1) {
    if ((int)threadIdx.x < st) red[threadIdx.x] += red[threadIdx.x + st];
    __syncthreads();
  }
  if (threadIdx.x == 0) part[blockIdx.x] = red[0];
}

__global__ __launch_bounds__(256) void finalize_scales_k(const float* __restrict__ part,
                                                         float* __restrict__ scales) {
  __shared__ float red[256];
  red[threadIdx.x] = part[blockIdx.x * 256 + threadIdx.x];
  __syncthreads();
  for (int st = 128; st > 0; st >>= 1) {
    if ((int)threadIdx.x < st) red[threadIdx.x] += red[threadIdx.x + st];
    __syncthreads();
  }
  if (threadIdx.x == 0) {
    float n = (blockIdx.x == 0) ? (float)(N_QKV * C_DIM) : (float)(C_DIM * C_DIM);
    scales[blockIdx.x] = fmaxf(red[0] / n, 1e-8f);
  }
}

// ---------------- ternarize -> bf16 (exact: {-1,0,1}) -----------------------
__global__ __launch_bounds__(256) void ternarize_k(const float* __restrict__ w,
                                                   ushort_t* __restrict__ wt, int n,
                                                   const float* __restrict__ scales,
                                                   int which) {
  int i = blockIdx.x * 256 + threadIdx.x;
  if (i < n) {
    float s = scales[which];
    float t = rintf(w[i] / s);           // round-half-even matches jnp.round
    wt[i] = f2bf(fminf(1.f, fmaxf(-1.f, t)));
  }
}

// ---------------- fp32 -> bf16 hi/lo split ----------------------------------
__global__ __launch_bounds__(256) void split_hl_k(const float* __restrict__ in,
                                                  ushort_t* __restrict__ hi,
                                                  ushort_t* __restrict__ lo, int n4) {
  int i = blockIdx.x * 256 + threadIdx.x;
  if (i < n4) {
    const float4 v = ((const float4*)in)[i];
    const float vv[4] = {v.x, v.y, v.z, v.w};
    ushort_t hh[4], ll[4];
#pragma unroll
    for (int j = 0; j < 4; ++j) {
      hh[j] = f2bf(vv[j]);
      ll[j] = f2bf(vv[j] - bf2f(hh[j]));
    }
    ((ushort4*)hi)[i] = make_ushort4(hh[0], hh[1], hh[2], hh[3]);
    ((ushort4*)lo)[i] = make_ushort4(ll[0], ll[1], ll[2], ll[3]);
  }
}

// ---------------- bf16 MFMA GEMM, A split hi/lo (qkv projection) ------------
// 128x128 tile, BK=64, 4 waves 2x2. Staging via global_load_lds width=16:
// linear LDS dest + inverse-XOR-swizzled GLOBAL src; XOR-swizzled ds_read
// (both-sides-or-neither rule). 2-barrier m97 loop.
__global__ __launch_bounds__(256) void gemm_bf16_hl(const ushort_t* __restrict__ Ah,
                                                    const ushort_t* __restrict__ Al,
                                                    const ushort_t* __restrict__ Bw,
                                                    float* __restrict__ C,
                                                    int Nd, int Kd) {
  __shared__ __align__(16) char lds[49152];   // Ah 16K | Al 16K | B 16K
  const int tid = threadIdx.x;
  const int bm = blockIdx.y << 7, bn = blockIdx.x << 7;
  const int w = tid >> 6, lane = tid & 63;
  const int wm = (w >> 1) << 6, wn = (w & 1) << 6;
  const int fr = lane & 15, fc = lane >> 4;

  // staging map: 4 16B-slots per tile per thread; slot=(i*256+tid) -> row=slot>>3,
  // src col pre-swizzled so the linear LDS image equals the swizzled layout.
  int srow[4], scol[4];
#pragma unroll
  for (int i = 0; i < 4; ++i) {
    const int slot = i * 256 + tid;
    const int r = slot >> 3, s = slot & 7;
    srow[i] = r;
    scol[i] = (s ^ (r & 7)) << 3;            // element offset within the 64-col row
  }

  f32x4 acc[4][4];
  const f32x4 z = {0.f, 0.f, 0.f, 0.f};
#pragma unroll
  for (int i = 0; i < 4; ++i)
#pragma unroll
    for (int j = 0; j < 4; ++j) acc[i][j] = z;

  for (int k0 = 0; k0 < Kd; k0 += 64) {
    __syncthreads();                         // previous compute done
#pragma unroll
    for (int i = 0; i < 4; ++i) {
      const int d16 = (i * 256 + tid) * 16;
      const size_t ga = (size_t)(bm + srow[i]) * Kd + k0 + scol[i];
      const size_t gb = (size_t)(bn + srow[i]) * Kd + k0 + scol[i];
      gll16((const char*)(Ah + ga), lds + d16);
      gll16((const char*)(Al + ga), lds + 16384 + d16);
      gll16((const char*)(Bw + gb), lds + 32768 + d16);
    }
    __syncthreads();                         // vmcnt drained -> tiles ready
#pragma unroll
    for (int ks = 0; ks < 2; ++ks) {
      short8 af[4], lf[4], bf[4];
#pragma unroll
      for (int i = 0; i < 4; ++i) {
        const int ra = wm + i * 16 + fr;
        const int ca = (ks * 64 + fc * 16) ^ ((ra & 7) << 4);
        af[i] = *(const short8*)(lds + ra * 128 + ca);
        lf[i] = *(const short8*)(lds + 16384 + ra * 128 + ca);
        const int rb = wn + i * 16 + fr;
        const int cbb = (ks * 64 + fc * 16) ^ ((rb & 7) << 4);
        bf[i] = *(const short8*)(lds + 32768 + rb * 128 + cbb);
      }
#pragma unroll
      for (int i = 0; i < 4; ++i)
#pragma unroll
        for (int j = 0; j < 4; ++j) {
          acc[i][j] = __builtin_amdgcn_mfma_f32_16x16x32_bf16(af[i], bf[j], acc[i][j], 0, 0, 0);
          acc[i][j] = __builtin_amdgcn_mfma_f32_16x16x32_bf16(lf[i], bf[j], acc[i][j], 0, 0, 0);
        }
    }
  }
#pragma unroll
  for (int i = 0; i < 4; ++i)
#pragma unroll
    for (int j = 0; j < 4; ++j) {
      float* cp = C + (size_t)(bm + wm + i * 16 + fc * 4) * Nd + bn + wn + j * 16 + fr;
#pragma unroll
      for (int r = 0; r < 4; ++r) cp[(size_t)r * Nd] = acc[i][j][r];
    }
}

// ---------------- bf16 MFMA GEMM, single-pass A (out projection) ------------
__global__ __launch_bounds__(256) void gemm_bf16(const ushort_t* __restrict__ A,
                                                 const ushort_t* __restrict__ Bw,
                                                 float* __restrict__ C,
                                                 int Nd, int Kd) {
  __shared__ __align__(16) char lds[32768];   // A 16K | B 16K
  const int tid = threadIdx.x;
  const int bm = blockIdx.y << 7, bn = blockIdx.x << 7;
  const int w = tid >> 6, lane = tid & 63;
  const int wm = (w >> 1) << 6, wn = (w & 1) << 6;
  const int fr = lane & 15, fc = lane >> 4;

  int srow[4], scol[4];
#pragma unroll
  for (int i = 0; i < 4; ++i) {
    const int slot = i * 256 + tid;
    const int r = slot >> 3, s = slot & 7;
    srow[i] = r;
    scol[i] = (s ^ (r & 7)) << 3;
  }

  f32x4 acc[4][4];
  const f32x4 z = {0.f, 0.f, 0.f, 0.f};
#pragma unroll
  for (int i = 0; i < 4; ++i)
#pragma unroll
    for (int j = 0; j < 4; ++j) acc[i][j] = z;

  for (int k0 = 0; k0 < Kd; k0 += 64) {
    __syncthreads();
#pragma unroll
    for (int i = 0; i < 4; ++i) {
      const int d16 = (i * 256 + tid) * 16;
      gll16((const char*)(A + (size_t)(bm + srow[i]) * Kd + k0 + scol[i]), lds + d16);
      gll16((const char*)(Bw + (size_t)(bn + srow[i]) * Kd + k0 + scol[i]), lds + 16384 + d16);
    }
    __syncthreads();
#pragma unroll
    for (int ks = 0; ks < 2; ++ks) {
      short8 af[4], bf[4];
#pragma unroll
      for (int i = 0; i < 4; ++i) {
        const int ra = wm + i * 16 + fr;
        af[i] = *(const short8*)(lds + ra * 128 + ((ks * 64 + fc * 16) ^ ((ra & 7) << 4)));
        const int rb = wn + i * 16 + fr;
        bf[i] = *(const short8*)(lds + 16384 + rb * 128 + ((ks * 64 + fc * 16) ^ ((rb & 7) << 4)));
      }
#pragma unroll
      for (int i = 0; i < 4; ++i)
#pragma unroll
        for (int j = 0; j < 4; ++j)
          acc[i][j] = __builtin_amdgcn_mfma_f32_16x16x32_bf16(af[i], bf[j], acc[i][j], 0, 0, 0);
    }
  }
#pragma unroll
  for (int i = 0; i < 4; ++i)
#pragma unroll
    for (int j = 0; j < 4; ++j) {
      float* cp = C + (size_t)(bm + wm + i * 16 + fc * 4) * Nd + bn + wn + j * 16 + fr;
#pragma unroll
      for (int r = 0; r < 4; ++r) cp[(size_t)r * Nd] = acc[i][j][r];
    }
}

// ---------------- prep_kv: per-(b,h,chunk) swizzled LDS images --------------
__global__ __launch_bounds__(256) void prep_kv_k(const float* __restrict__ qkv,
                                                 char* __restrict__ img) {
  __shared__ __align__(16) char sm[24576];
  const int tid = threadIdx.x;
  const int c = blockIdx.x & 31, gg = blockIdx.x >> 5;
  const int h = gg & 15, b = gg >> 4;
  const int key = tid >> 2, dg = tid & 3;
  const float* kp = qkv + (size_t)b * T_SEQ * N_QKV +
                    (size_t)(c * 64 + key) * N_QKV + C_DIM + (h << 6) + dg * 16;
  const float4 k0 = *(const float4*)(kp + 0);
  const float4 k1 = *(const float4*)(kp + 4);
  const float4 k2 = *(const float4*)(kp + 8);
  const float4 k3 = *(const float4*)(kp + 12);
  const float4 v0 = *(const float4*)(kp + C_DIM + 0);
  const float4 v1 = *(const float4*)(kp + C_DIM + 4);
  const float4 v2 = *(const float4*)(kp + C_DIM + 8);
  const float4 v3 = *(const float4*)(kp + C_DIM + 12);
  const float kv[16] = {k0.x,k0.y,k0.z,k0.w, k1.x,k1.y,k1.z,k1.w,
                        k2.x,k2.y,k2.z,k2.w, k3.x,k3.y,k3.z,k3.w};
  const float vv[16] = {v0.x,v0.y,v0.z,v0.w, v1.x,v1.y,v1.z,v1.w,
                        v2.x,v2.y,v2.z,v2.w, v3.x,v3.y,v3.z,v3.w};
  short8 khi0, khi1, klo0, klo1;
#pragma unroll
  for (int j = 0; j < 8; ++j) {
    const float x0 = kv[j], x1 = kv[8 + j];
    const unsigned short h0 = f2bf(x0), h1 = f2bf(x1);
    khi0[j] = (short)h0; khi1[j] = (short)h1;
    klo0[j] = (short)f2bf(x0 - bf2f(h0));
    klo1[j] = (short)f2bf(x1 - bf2f(h1));
  }
  const int sw = (key & 7) << 4;
  const int b0 = key * 128 + ((dg * 32) ^ sw);
  const int b1 = key * 128 + ((dg * 32 + 16) ^ sw);
  *(short8*)(sm + b0) = khi0;        *(short8*)(sm + b1) = khi1;
  *(short8*)(sm + 8192 + b0) = klo0; *(short8*)(sm + 8192 + b1) = klo1;
#pragma unroll
  for (int i = 0; i < 16; ++i) {
    const int d = dg * 16 + i;
    *(short*)(sm + 16384 + d * 128 + ((key * 2) ^ ((d & 7) << 4))) = (short)f2bf(vv[i]);
  }
  __syncthreads();
  int4* dst = (int4*)(img + (size_t)blockIdx.x * 24576);
  const int4* src = (const int4*)sm;
#pragma unroll
  for (int i = 0; i < 6; ++i) dst[i * 256 + tid] = src[i * 256 + tid];
}

// ---------------- paired-tile MFMA flash attention (R5 structure) -----------
// Double-buffered 24KB chunk images via global_load_lds: loads for chunk c+1
// in flight during compute of chunk c (intra-block overlap; grid 512 = 2
// blocks/CU so inter-block TLP cannot be relied on -- R7 lesson).
struct TS { f32x4 O[4]; float m[4]; float l[4]; };

__device__ __forceinline__ void tile_step(const char* khp, const char* klp,
                                          const char* vTp, char* pp,
                                          const short8* qh, const short8* ql,
                                          TS& st, const bool diag,
                                          const int w, const int lg, const int lr) {
  f32x4 s4[4];
  const f32x4 z = {0.f, 0.f, 0.f, 0.f};
#pragma unroll
  for (int f = 0; f < 4; ++f) s4[f] = z;
#pragma unroll
  for (int s = 0; s < 2; ++s) {
    const int cb = s * 64 + lg * 16;
#pragma unroll
    for (int f = 0; f < 4; ++f) {
      const int row = lr + 16 * f;
      const int byt = row * 128 + (cb ^ ((row & 7) << 4));
      const short8 bh8 = *(const short8*)(khp + byt);
      const short8 bl8 = *(const short8*)(klp + byt);
      s4[f] = __builtin_amdgcn_mfma_f32_16x16x32_bf16(qh[s], bh8, s4[f], 0, 0, 0);
      s4[f] = __builtin_amdgcn_mfma_f32_16x16x32_bf16(ql[s], bh8, s4[f], 0, 0, 0);
      s4[f] = __builtin_amdgcn_mfma_f32_16x16x32_bf16(qh[s], bl8, s4[f], 0, 0, 0);
    }
  }
  if (diag) {
#pragma unroll
    for (int f = 0; f < 4; ++f) {
      const int kg = 16 * f + lr;
#pragma unroll
      for (int r = 0; r < 4; ++r) {
        const int qg = w * 16 + lg * 4 + r;
        if (kg > qg) s4[f][r] = -1e30f;
      }
    }
  }
  float mc[4], resc[4], ps[4];
#pragma unroll
  for (int r = 0; r < 4; ++r)
    mc[r] = fmaxf(fmaxf(s4[0][r], s4[1][r]), fmaxf(s4[2][r], s4[3][r]));
#pragma unroll
  for (int d = 1; d <= 8; d <<= 1)
#pragma unroll
    for (int r = 0; r < 4; ++r) mc[r] = fmaxf(mc[r], __shfl_xor(mc[r], d));
#pragma unroll
  for (int r = 0; r < 4; ++r) {
    const float mn = fmaxf(st.m[r], mc[r]);
    resc[r] = __expf(st.m[r] - mn);
    st.m[r] = mn;
    ps[r] = 0.f;
  }
#pragma unroll
  for (int f = 0; f < 4; ++f)
#pragma unroll
    for (int r = 0; r < 4; ++r) {
      const float p = __expf(s4[f][r] - st.m[r]);
      s4[f][r] = p;
      ps[r] += p;
    }
#pragma unroll
  for (int d = 1; d <= 8; d <<= 1)
#pragma unroll
    for (int r = 0; r < 4; ++r) ps[r] += __shfl_xor(ps[r], d);
#pragma unroll
  for (int r = 0; r < 4; ++r) st.l[r] = st.l[r] * resc[r] + ps[r];
#pragma unroll
  for (int n = 0; n < 4; ++n)
#pragma unroll
    for (int r = 0; r < 4; ++r) st.O[n][r] *= resc[r];
#pragma unroll
  for (int f = 0; f < 4; ++f)
#pragma unroll
    for (int r = 0; r < 4; ++r) {
      const int q = lg * 4 + r;
      *(short*)(pp + q * 128 + (((lr + 16 * f) * 2) ^ ((q & 7) << 4))) = (short)f2bf(s4[f][r]);
    }
#pragma unroll
  for (int s = 0; s < 2; ++s) {
    const int cb = s * 64 + lg * 16;
    const short8 pa = *(const short8*)(pp + lr * 128 + (cb ^ ((lr & 7) << 4)));
#pragma unroll
    for (int n = 0; n < 4; ++n) {
      const int d = lr + 16 * n;
      const short8 vb = *(const short8*)(vTp + d * 128 + (cb ^ ((d & 7) << 4)));
      st.O[n] = __builtin_amdgcn_mfma_f32_16x16x32_bf16(pa, vb, st.O[n], 0, 0, 0);
    }
  }
}

__device__ __forceinline__ void load_q(const float* base, int qt, int h,
                                       int w, int lg, int lr,
                                       short8* qh, short8* ql) {
  const float* qrow = base + (size_t)(qt * 64 + w * 16 + lr) * N_QKV + (h << 6);
#pragma unroll
  for (int s = 0; s < 2; ++s) {
    const float4 a0 = *(const float4*)(qrow + s * 32 + lg * 8);
    const float4 a1 = *(const float4*)(qrow + s * 32 + lg * 8 + 4);
    const float xv[8] = {a0.x, a0.y, a0.z, a0.w, a1.x, a1.y, a1.z, a1.w};
#pragma unroll
    for (int j = 0; j < 8; ++j) {
      const float xs = xv[j] * 0.125f;       // fold 1/sqrt(64)
      const unsigned short hs = f2bf(xs);
      qh[s][j] = (short)hs;
      ql[s][j] = (short)f2bf(xs - bf2f(hs));
    }
  }
}

__device__ __forceinline__ void store_o(ushort_t* oh, TS& st,
                                        int b, int qt, int h,
                                        int w, int lg, int lr) {
  float inv[4];
#pragma unroll
  for (int r = 0; r < 4; ++r) inv[r] = 1.f / st.l[r];
  const size_t ob = (size_t)(b * T_SEQ + qt * 64 + w * 16 + lg * 4) * C_DIM + (h << 6) + lr;
#pragma unroll
  for (int r = 0; r < 4; ++r)
#pragma unroll
    for (int n = 0; n < 4; ++n)
      oh[ob + (size_t)r * C_DIM + 16 * n] = f2bf(st.O[n][r] * inv[r]);
}

__global__ __launch_bounds__(256) void attn2_k(const float* __restrict__ qkv,
                                               const char* __restrict__ img,
                                               ushort_t* __restrict__ oh) {
  __shared__ __align__(16) char smem[57344];   // buf0 24K | buf1 24K | P 4x2K
  const int tid  = threadIdx.x;
  const int lane = tid & 63;
  const int w    = tid >> 6;
  const int lg   = lane >> 4;
  const int lr   = lane & 15;
  char* const pp = smem + 49152 + (w << 11);

  // gg in low bits -> all 16 p-blocks of one (b,h) land on one XCD (L2-hot img)
  const int bx = blockIdx.x;
  const int p  = (bx >> 3) & 15;
  const int gg = ((bx >> 7) << 3) | (bx & 7);
  const int h  = gg & 15, b = gg >> 4;
  const int qtA = p, qtB = 31 - p;

  const float* base = qkv + (size_t)b * T_SEQ * N_QKV;
  const char* img_gg = img + (size_t)gg * 32 * 24576;

  short8 qhA[2], qlA[2], qhB[2], qlB[2];
  load_q(base, qtA, h, w, lg, lr, qhA, qlA);
  load_q(base, qtB, h, w, lg, lr, qhB, qlB);

  TS stA, stB;
#pragma unroll
  for (int n = 0; n < 4; ++n) {
    const f32x4 z = {0.f, 0.f, 0.f, 0.f};
    stA.O[n] = z; stB.O[n] = z;
    stA.m[n] = -1e30f; stB.m[n] = -1e30f;
    stA.l[n] = 0.f; stB.l[n] = 0.f;
  }

  // prologue: issue chunk 0 into buf0
#pragma unroll
  for (int i = 0; i < 6; ++i)
    gll16(img_gg + i * 4096 + tid * 16, smem + i * 4096 + tid * 16);

  int cur = 0;
  for (int c = 0; c <= qtB; ++c) {
    __syncthreads();                         // drains outstanding loads
    if (c < qtB) {
      const char* src = img_gg + (size_t)(c + 1) * 24576;
      char* dst = smem + (cur ^ 1) * 24576;
#pragma unroll
      for (int i = 0; i < 6; ++i)
        gll16(src + i * 4096 + tid * 16, dst + i * 4096 + tid * 16);
    }
    const char* kh = smem + cur * 24576;
    tile_step(kh, kh + 8192, kh + 16384, pp, qhB, qlB, stB, c == qtB, w, lg, lr);
    if (c <= qtA)
      tile_step(kh, kh + 8192, kh + 16384, pp, qhA, qlA, stA, c == qtA, w, lg, lr);
    cur ^= 1;
  }

  store_o(oh, stA, b, qtA, h, w, lg, lr);
  store_o(oh, stB, b, qtB, h, w, lg, lr);
}

// ---------------- launch ----------------------------------------------------
extern "C" void kernel_launch(void* const* d_in, const int* in_sizes, int n_in,
                              void* d_out, int out_size, void* d_ws, size_t ws_size,
                              hipStream_t stream) {
  const float* x      = (const float*)d_in[0];   // [4096][1024]
  const float* w_qkv  = (const float*)d_in[1];   // [3072][1024]
  const float* w_out  = (const float*)d_in[2];   // [1024][1024]
  float* out = (float*)d_out;                    // [4096][1024]

  // layout (img aliases wt_qkv, which is dead after gemm1; stream-ordered)
  char* pch = (char*)d_ws;
  ushort_t* wt_out = (ushort_t*)pch;  pch += (size_t)C_DIM * C_DIM * 2;    // 2MB
  ushort_t* xh     = (ushort_t*)pch;  pch += (size_t)M_ROWS * C_DIM * 2;   // 8MB
  ushort_t* xl     = (ushort_t*)pch;  pch += (size_t)M_ROWS * C_DIM * 2;   // 8MB
  float*    qkv    = (float*)pch;     pch += (size_t)M_ROWS * N_QKV * 4;   // 48MB
  ushort_t* wt_qkv = (ushort_t*)pch;                                       // 6MB..
  char*     img    = pch;             pch += (size_t)1024 * 24576;         // 25.2MB
  float*    part   = (float*)pch;     pch += 512 * 4;
  float*    scales = (float*)pch;
  ushort_t* ah = xh;   // x hi dead after gemm1 -> reuse for attn output

  hipLaunchKernelGGL(abs_partial_k, dim3(256), dim3(256), 0, stream,
                     w_qkv, N_QKV * C_DIM, part);
  hipLaunchKernelGGL(abs_partial_k, dim3(256), dim3(256), 0, stream,
                     w_out, C_DIM * C_DIM, part + 256);
  hipLaunchKernelGGL(finalize_scales_k, dim3(2), dim3(256), 0, stream, part, scales);

  hipLaunchKernelGGL(ternarize_k, dim3((N_QKV * C_DIM) / 256), dim3(256), 0, stream,
                     w_qkv, wt_qkv, N_QKV * C_DIM, scales, 0);
  hipLaunchKernelGGL(ternarize_k, dim3((C_DIM * C_DIM) / 256), dim3(256), 0, stream,
                     w_out, wt_out, C_DIM * C_DIM, scales, 1);

  hipLaunchKernelGGL(split_hl_k, dim3((M_ROWS * C_DIM / 4) / 256), dim3(256), 0, stream,
                     x, xh, xl, M_ROWS * C_DIM / 4);

  // qkv = (xh+xl) @ wt_qkv^T
  hipLaunchKernelGGL(gemm_bf16_hl, dim3(N_QKV / 128, M_ROWS / 128), dim3(256), 0, stream,
                     xh, xl, wt_qkv, qkv, N_QKV, C_DIM);

  // K/V chunk images (overwrites wt_qkv region — dead now)
  hipLaunchKernelGGL(prep_kv_k, dim3(1024), dim3(256), 0, stream, qkv, img);

  // attention -> bf16 (out-proj not tie-sensitive; single precision stream)
  hipLaunchKernelGGL(attn2_k, dim3(512), dim3(256), 0, stream, qkv, img, ah);

  // out = ah @ wt_out^T
  hipLaunchKernelGGL(gemm_bf16, dim3(C_DIM / 128, M_ROWS / 128), dim3(256), 0, stream,
                     ah, wt_out, out, C_DIM, C_DIM);
}